// Round 5
// baseline (519.046 us; speedup 1.0000x reference)
//
#include <hip/hip_runtime.h>
#include <hip/hip_bf16.h>

typedef __bf16 bf16;
typedef unsigned int u32;
typedef __attribute__((ext_vector_type(8))) __bf16 bf16x8;
typedef __attribute__((ext_vector_type(4))) __bf16 bf16x4;
typedef __attribute__((ext_vector_type(4))) float f32x4;

#define Bsz 256
#define Tsz 256
#define Csz 384
#define Hn  6
#define Dh  64
#define NQKV 1152   // 3 mats * 6 heads * 64

#define MFMA16(a, b, c) __builtin_amdgcn_mfma_f32_16x16x32_bf16(a, b, c, 0, 0, 0)

typedef __attribute__((address_space(3))) u32 lds_u32;
typedef __attribute__((address_space(1))) const u32 gbl_u32;
__device__ __forceinline__ void gl2lds16(const void* g, void* l) {
    // async global->LDS, 16B/lane; LDS dest = wave-uniform base + lane*16
    __builtin_amdgcn_global_load_lds((gbl_u32*)g, (lds_u32*)l, 16, 0, 0);
}

__device__ __forceinline__ float redmax16(float x) {
    x = fmaxf(x, __shfl_xor(x, 1));
    x = fmaxf(x, __shfl_xor(x, 2));
    x = fmaxf(x, __shfl_xor(x, 4));
    x = fmaxf(x, __shfl_xor(x, 8));
    return x;
}
__device__ __forceinline__ float redsum16(float x) {
    x += __shfl_xor(x, 1);
    x += __shfl_xor(x, 2);
    x += __shfl_xor(x, 4);
    x += __shfl_xor(x, 8);
    return x;
}

// ---------------- x: fp32 -> bf16 ----------------
__global__ __launch_bounds__(256) void convert_x(
    const float* __restrict__ x, bf16* __restrict__ xb)
{
    size_t i = ((size_t)blockIdx.x * 256 + threadIdx.x) * 8;
    float4 f0 = *(const float4*)&x[i];
    float4 f1 = *(const float4*)&x[i + 4];
    bf16x8 o;
    o[0] = (bf16)f0.x; o[1] = (bf16)f0.y; o[2] = (bf16)f0.z; o[3] = (bf16)f0.w;
    o[4] = (bf16)f1.x; o[5] = (bf16)f1.y; o[6] = (bf16)f1.z; o[7] = (bf16)f1.w;
    *(bf16x8*)&xb[i] = o;
}

// ---------------- weights: fp32 -> bf16, B^T [n][k] layout ----------------
__global__ __launch_bounds__(384) void prep_w(
    const float* __restrict__ Wq, const float* __restrict__ Wk,
    const float* __restrict__ Wv, const float* __restrict__ Wp,
    bf16* __restrict__ Btqkv, bf16* __restrict__ Bpt)
{
    const int n = blockIdx.x, k = threadIdx.x;
    if (n < NQKV) {
        int wi = n / Csz, rem = n - wi * Csz, h = rem >> 6, d = rem & 63;
        const float* W = wi == 0 ? Wq : (wi == 1 ? Wk : Wv);
        Btqkv[(size_t)n * Csz + k] = (bf16)W[((size_t)h * Csz + k) * Dh + d];
    } else {
        int n2 = n - NQKV;
        Bpt[(size_t)n2 * Csz + k] = (bf16)Wp[(size_t)k * Csz + n2];
    }
}

// ---------------- QKV as one 65536x1152x384 GEMM (m97 structure) ----------------
// Grid (n=9 FASTEST, m=512 slowest): concurrent window covers all n-tiles of
// ~57 m-tiles -> A re-reads L2/L3-hit (round-4: m-fastest streamed A 9x, 224MB).
// q,k row-major [B,H,T,D]; v stored TRANSPOSED [B,H,D,T] (packs 4 t-consecutive
// acc into one 8B store; feeds attn's B-operand directly).
__global__ __launch_bounds__(256) void qkv_gemm(
    const bf16* __restrict__ A, const bf16* __restrict__ Bt,
    bf16* __restrict__ q, bf16* __restrict__ k, bf16* __restrict__ vt)
{
    __shared__ bf16 As[128][64];
    __shared__ bf16 Bs[128][64];
    const int tid = threadIdx.x, w = tid >> 6, lane = tid & 63;
    const int l4 = lane & 15, quad = lane >> 4;
    const int wm = w & 1, wn = w >> 1;
    const int n0 = blockIdx.x * 128, m0 = blockIdx.y * 128;
    const int srow = lane >> 3;
    const int skk  = (lane & 7) * 8;

    f32x4 acc[4][4] = {};

    for (int kc = 0; kc < Csz / 64; ++kc) {
        #pragma unroll
        for (int i = 0; i < 4; ++i) {
            int r = (w * 4 + i) * 8 + srow;
            gl2lds16(&A [(size_t)(m0 + r) * Csz + kc * 64 + skk],
                     (char*)&As[0][0] + (w * 4 + i) * 1024);
            gl2lds16(&Bt[(size_t)(n0 + r) * Csz + kc * 64 + skk],
                     (char*)&Bs[0][0] + (w * 4 + i) * 1024);
        }
        __syncthreads();
        #pragma unroll
        for (int ks = 0; ks < 2; ++ks) {
            bf16x8 af[4], bfr[4];
            #pragma unroll
            for (int mt = 0; mt < 4; ++mt)
                af[mt] = *(const bf16x8*)&As[wm * 64 + mt * 16 + l4][ks * 32 + quad * 8];
            #pragma unroll
            for (int nt = 0; nt < 4; ++nt)
                bfr[nt] = *(const bf16x8*)&Bs[wn * 64 + nt * 16 + l4][ks * 32 + quad * 8];
            #pragma unroll
            for (int mt = 0; mt < 4; ++mt)
                #pragma unroll
                for (int nt = 0; nt < 4; ++nt)
                    acc[mt][nt] = MFMA16(af[mt], bfr[nt], acc[mt][nt]);
        }
        __syncthreads();
    }

    const int wi = n0 / Csz;   // uniform per block (128 | 384)
    if (wi == 2) {
        // v transposed: vt[((b*Hn+h)*Dh + d)*Tsz + t], 4 consecutive t packed
        #pragma unroll
        for (int nt = 0; nt < 4; ++nt) {
            int rem = n0 - 2 * Csz + wn * 64 + nt * 16 + l4;
            int h = rem >> 6, d = rem & 63;
            #pragma unroll
            for (int mt = 0; mt < 4; ++mt) {
                int m = m0 + wm * 64 + mt * 16 + quad * 4;
                int b = m >> 8, t = m & 255;
                bf16x4 pk;
                pk[0] = (bf16)acc[mt][nt][0]; pk[1] = (bf16)acc[mt][nt][1];
                pk[2] = (bf16)acc[mt][nt][2]; pk[3] = (bf16)acc[mt][nt][3];
                *(bf16x4*)&vt[(((size_t)(b * Hn + h)) * Dh + d) * Tsz + t] = pk;
            }
        }
    } else {
        bf16* outp = wi == 0 ? q : k;
        #pragma unroll
        for (int nt = 0; nt < 4; ++nt) {
            int rem = n0 - wi * Csz + wn * 64 + nt * 16 + l4;
            int h = rem >> 6, d = rem & 63;
            #pragma unroll
            for (int mt = 0; mt < 4; ++mt)
                #pragma unroll
                for (int r = 0; r < 4; ++r) {
                    int m = m0 + wm * 64 + mt * 16 + quad * 4 + r;
                    int b = m >> 8, t = m & 255;
                    outp[(((size_t)(b * Hn + h)) * Tsz + t) * Dh + d] = (bf16)acc[mt][nt][r];
                }
        }
    }
}

// ---------------- Flash attention, MFMA, barrier-free ----------------
// One block per (b,h,qtile-of-64); wave w owns q rows [qt*64+w*16, +16).
// K row-major and V^T are read as B-fragments DIRECTLY from global (16B loads,
// tiles L1/L2-resident, shared across the 4 qt-blocks of the head) -> no LDS
// staging, no __syncthreads. Only wave-private P roundtrip LDS remains.
__global__ __launch_bounds__(256) void attn_mfma(
    const bf16* __restrict__ q, const bf16* __restrict__ k,
    const bf16* __restrict__ vt, bf16* __restrict__ att)
{
    __shared__ bf16 Pl[4][16][72];   // per-wave [qrow][s]
    const float SCL = 0.18033688f;   // 0.125 * log2(e)
    const int tid = threadIdx.x, w = tid >> 6, lane = tid & 63;
    const int l4 = lane & 15, quad = lane >> 4;
    const int blk = blockIdx.x;
    const int bh = blk >> 2, qt = blk & 3;
    const int b = bh / Hn, h = bh % Hn;
    const bf16* qb  = q  + (size_t)bh * Tsz * Dh;
    const bf16* kb  = k  + (size_t)bh * Tsz * Dh;
    const bf16* vtb = vt + (size_t)bh * Dh * Tsz;   // [d][s]

    const int trow = qt * 64 + w * 16 + l4;
    const bf16x8 qa0 = *(const bf16x8*)&qb[trow * Dh + quad * 8];
    const bf16x8 qa1 = *(const bf16x8*)&qb[trow * Dh + 32 + quad * 8];

    f32x4 o[4] = {};
    float mrun[4] = {-3.0e38f, -3.0e38f, -3.0e38f, -3.0e38f};
    float lrun[4] = {0.f, 0.f, 0.f, 0.f};

    for (int kt = 0; kt <= qt; ++kt) {
        // S = Q.K^T ; K B-frags straight from global (row nt*16+l4, k=d contiguous)
        f32x4 sc[4] = {};
        #pragma unroll
        for (int nt = 0; nt < 4; ++nt) {
            const bf16* kr = &kb[(kt * 64 + nt * 16 + l4) * Dh];
            bf16x8 b0 = *(const bf16x8*)&kr[quad * 8];
            bf16x8 b1 = *(const bf16x8*)&kr[32 + quad * 8];
            sc[nt] = MFMA16(qa0, b0, sc[nt]);
            sc[nt] = MFMA16(qa1, b1, sc[nt]);
        }

        // scale + causal mask + online softmax (C-row = quad*4+r, col = l4)
        float mnew[4], alpha[4];
        #pragma unroll
        for (int r = 0; r < 4; ++r) {
            int tg = qt * 64 + w * 16 + quad * 4 + r;
            float mx = mrun[r];
            #pragma unroll
            for (int nt = 0; nt < 4; ++nt) {
                float sv = sc[nt][r] * SCL;        // log2-domain
                int sg = kt * 64 + nt * 16 + l4;
                if (sg > tg) sv = -1.0e30f;
                sc[nt][r] = sv;
                mx = fmaxf(mx, sv);
            }
            mx = redmax16(mx);
            mnew[r] = mx;
            alpha[r] = __builtin_amdgcn_exp2f(mrun[r] - mx);
            mrun[r] = mx;
        }
        #pragma unroll
        for (int r = 0; r < 4; ++r) {
            float sm = 0.f;
            #pragma unroll
            for (int nt = 0; nt < 4; ++nt) {
                float e = __builtin_amdgcn_exp2f(sc[nt][r] - mnew[r]);
                sc[nt][r] = e;
                sm += e;
            }
            sm = redsum16(sm);
            lrun[r] = lrun[r] * alpha[r] + sm;
        }
        #pragma unroll
        for (int nt = 0; nt < 4; ++nt)
            #pragma unroll
            for (int r = 0; r < 4; ++r) o[nt][r] *= alpha[r];

        // P: C-layout regs -> wave-private LDS -> A-layout frags (HW-ordered)
        #pragma unroll
        for (int nt = 0; nt < 4; ++nt)
            #pragma unroll
            for (int r = 0; r < 4; ++r)
                Pl[w][quad * 4 + r][nt * 16 + l4] = (bf16)sc[nt][r];
        bf16x8 pa0 = *(const bf16x8*)&Pl[w][l4][quad * 8];
        bf16x8 pa1 = *(const bf16x8*)&Pl[w][l4][32 + quad * 8];

        // PV ; V^T B-frags straight from global (row d=nt*16+l4, k=s contiguous)
        #pragma unroll
        for (int nt = 0; nt < 4; ++nt) {
            const bf16* vr = &vtb[(nt * 16 + l4) * Tsz + kt * 64];
            bf16x8 v0 = *(const bf16x8*)&vr[quad * 8];
            bf16x8 v1 = *(const bf16x8*)&vr[32 + quad * 8];
            o[nt] = MFMA16(pa0, v0, o[nt]);
            o[nt] = MFMA16(pa1, v1, o[nt]);
        }
    }

    #pragma unroll
    for (int r = 0; r < 4; ++r) {
        float inv = 1.f / lrun[r];
        int tg = qt * 64 + w * 16 + quad * 4 + r;
        #pragma unroll
        for (int nt = 0; nt < 4; ++nt)
            att[((size_t)(b * Tsz + tg)) * Csz + h * Dh + nt * 16 + l4] =
                (bf16)(o[nt][r] * inv);
    }
}

// ---------------- Output projection as 65536x384x384 GEMM ----------------
__global__ __launch_bounds__(256) void proj_gemm(
    const bf16* __restrict__ A, const bf16* __restrict__ Bt,
    const float* __restrict__ bias, float* __restrict__ out)
{
    __shared__ bf16 As[128][64];
    __shared__ bf16 Bs[128][64];
    const int tid = threadIdx.x, w = tid >> 6, lane = tid & 63;
    const int l4 = lane & 15, quad = lane >> 4;
    const int wm = w & 1, wn = w >> 1;
    const int n0 = blockIdx.x * 128, m0 = blockIdx.y * 128;
    const int srow = lane >> 3;
    const int skk  = (lane & 7) * 8;

    f32x4 acc[4][4] = {};

    for (int kc = 0; kc < Csz / 64; ++kc) {
        #pragma unroll
        for (int i = 0; i < 4; ++i) {
            int r = (w * 4 + i) * 8 + srow;
            gl2lds16(&A [(size_t)(m0 + r) * Csz + kc * 64 + skk],
                     (char*)&As[0][0] + (w * 4 + i) * 1024);
            gl2lds16(&Bt[(size_t)(n0 + r) * Csz + kc * 64 + skk],
                     (char*)&Bs[0][0] + (w * 4 + i) * 1024);
        }
        __syncthreads();
        #pragma unroll
        for (int ks = 0; ks < 2; ++ks) {
            bf16x8 af[4], bfr[4];
            #pragma unroll
            for (int mt = 0; mt < 4; ++mt)
                af[mt] = *(const bf16x8*)&As[wm * 64 + mt * 16 + l4][ks * 32 + quad * 8];
            #pragma unroll
            for (int nt = 0; nt < 4; ++nt)
                bfr[nt] = *(const bf16x8*)&Bs[wn * 64 + nt * 16 + l4][ks * 32 + quad * 8];
            #pragma unroll
            for (int mt = 0; mt < 4; ++mt)
                #pragma unroll
                for (int nt = 0; nt < 4; ++nt)
                    acc[mt][nt] = MFMA16(af[mt], bfr[nt], acc[mt][nt]);
        }
        __syncthreads();
    }

    #pragma unroll
    for (int nt = 0; nt < 4; ++nt) {
        int n = n0 + wn * 64 + nt * 16 + l4;
        float bv = bias[n];
        #pragma unroll
        for (int mt = 0; mt < 4; ++mt)
            #pragma unroll
            for (int r = 0; r < 4; ++r) {
                int m = m0 + wm * 64 + mt * 16 + quad * 4 + r;
                out[(size_t)m * Csz + n] = acc[mt][nt][r] + bv;
            }
    }
}

extern "C" void kernel_launch(void* const* d_in, const int* in_sizes, int n_in,
                              void* d_out, int out_size, void* d_ws, size_t ws_size,
                              hipStream_t stream)
{
    const float* x  = (const float*)d_in[0];
    const float* Wq = (const float*)d_in[1];
    const float* Wk = (const float*)d_in[2];
    const float* Wv = (const float*)d_in[3];
    const float* Wp = (const float*)d_in[4];
    const float* bp = (const float*)d_in[5];
    float* out = (float*)d_out;

    const size_t npe = (size_t)Bsz * Tsz * Csz;   // 25,165,824 elems
    bf16* xb    = (bf16*)d_ws;          // [65536,384]; reused as att after qkv
    bf16* att   = xb;                   // alias: xb dead once qkv_gemm completes
    bf16* q     = xb + npe;             // [B,H,T,D]
    bf16* k     = q  + npe;             // [B,H,T,D]
    bf16* vt    = k  + npe;             // [B,H,D,T]  (transposed)
    bf16* Btqkv = vt + npe;             // [1152,384]
    bf16* Bpt   = Btqkv + (size_t)NQKV * Csz;   // [384,384]

    convert_x<<<npe / 2048, 256, 0, stream>>>(x, xb);
    prep_w<<<NQKV + Csz, 384, 0, stream>>>(Wq, Wk, Wv, Wp, Btqkv, Bpt);
    qkv_gemm<<<dim3(NQKV / 128, Bsz * Tsz / 128), 256, 0, stream>>>(xb, Btqkv, q, k, vt);
    attn_mfma<<<Bsz * Hn * 4, 256, 0, stream>>>(q, k, vt, att);
    proj_gemm<<<dim3(Csz / 128, Bsz * Tsz / 128), 256, 0, stream>>>(att, Bpt, bp, out);
}